// Round 9
// baseline (356.884 us; speedup 1.0000x reference)
//
#include <hip/hip_runtime.h>
#include <math.h>

typedef _Float16 f16;
typedef _Float16 f16x2 __attribute__((ext_vector_type(2)));
typedef _Float16 f16x4 __attribute__((ext_vector_type(4)));
typedef _Float16 f16x8 __attribute__((ext_vector_type(8)));

#if defined(__has_builtin)
#if __has_builtin(__builtin_amdgcn_fdot2)
#define USE_FDOT2 1
#endif
#if __has_builtin(__builtin_amdgcn_exp2f)
#define USE_EXP2 1
#endif
#endif

__device__ __forceinline__ float fdot2f(f16x2 a, f16x2 b, float c) {
#ifdef USE_FDOT2
    return __builtin_amdgcn_fdot2(a, b, c, false);
#else
    return c + (float)a.x * (float)b.x + (float)a.y * (float)b.y;
#endif
}
__device__ __forceinline__ float exp2fast(float a) {
#ifdef USE_EXP2
    return __builtin_amdgcn_exp2f(a);
#else
    return exp2f(a);
#endif
}

namespace {
// 192 real kv rows (V=2 x 6 in-range t2 x NN=4 x DD=4); 320 zero rows folded analytically.
constexpr int NKV = 192, NVP = 96;
constexpr int KS  = 40;                 // f16 per k row (32 data + 8 pad)
constexpr int VSP = 72;                 // f16 per v pair-row (64 data + 8 pad)
constexpr int QS2 = 40;                 // f16 per q row in LDS (16B-aligned rows)
constexpr int KBYTES = NKV * KS * 2;    // 15360
constexpr int VBYTES = NVP * VSP * 2;   // 13824
constexpr int QBYTES = 128 * QS2 * 2;   // 10240
constexpr float C1  = 0.2550600f;       // (1/sqrt(32)) * log2(e)
constexpr float CZN = -5.7707801f;      // -4*log2(e)  (fixed softmax shift, scores are tiny)
constexpr float CZV = 2.5511480f;       // CZN + log2(320): 320 identical zero-token kv rows
}

// LayerNorm one 64-ch token row into PACKED f16x2[32] (32 VGPRs). All indices static.
__device__ __forceinline__ void ln_row_f16(const float* __restrict__ xrow,
                                           const float* __restrict__ ls,
                                           const float* __restrict__ lb,
                                           f16x2 h2[32]) {
    float s = 0.f, ss = 0.f;
    #pragma unroll
    for (int i = 0; i < 16; ++i) {
        const float4 t = ((const float4*)xrow)[i];
        s  += (t.x + t.y) + (t.z + t.w);
        ss += t.x*t.x + t.y*t.y + t.z*t.z + t.w*t.w;
        h2[2*i]   = (f16x2){(f16)t.x, (f16)t.y};
        h2[2*i+1] = (f16x2){(f16)t.z, (f16)t.w};
    }
    const float mean = s * 0.015625f;
    const float rstd = rsqrtf(ss * 0.015625f - mean*mean + 1e-5f);
    #pragma unroll
    for (int i = 0; i < 32; ++i) {
        const float a0 = ((float)h2[i].x - mean) * rstd * ls[2*i]   + lb[2*i];
        const float a1 = ((float)h2[i].y - mean) * rstd * ls[2*i+1] + lb[2*i+1];
        h2[i] = (f16x2){(f16)a0, (f16)a1};
    }
}

// acc[0..NACC) += h2(64 ch packed) @ W (row stride `stride`), weights wave-uniform.
// MUST be fully unrolled: a runtime fp index sends h2[] to scratch (rule #20;
// r3-r5 regression: partial unroll -> 67MB scratch writes, 4x slowdown).
template<int NACC>
__device__ __forceinline__ void projh(const f16x2* __restrict__ h2,
                                      const float* __restrict__ wbase,
                                      const int stride, float* __restrict__ acc) {
    #pragma unroll
    for (int fp = 0; fp < 32; ++fp) {
        const float h0 = (float)h2[fp].x, h1 = (float)h2[fp].y;
        const float* w0 = wbase + (2*fp) * stride;
        const float* w1 = w0 + stride;
        #pragma unroll
        for (int j = 0; j < NACC; ++j)
            acc[j] = fmaf(h0, w0[j], fmaf(h1, w1[j], acc[j]));
    }
}

// ---------------- Kernel 1: per-(window,head) attention, o -> d_out (f16) ----------------
__global__ __launch_bounds__(256, 3) void k_att(
    const float* __restrict__ x,
    const float* __restrict__ ln1_s, const float* __restrict__ ln1_b,
    const float* __restrict__ Wq, const float* __restrict__ Wkv, const float* __restrict__ bkv,
    f16* __restrict__ o_out)
{
    __shared__ __align__(16) char smem[KBYTES + VBYTES + QBYTES];  // 39424 B
    f16* kl = (f16*)smem;                           // [192][KS]
    f16* vl = (f16*)(smem + KBYTES);                // [96 pairs][VSP]
    f16* ql = (f16*)(smem + KBYTES + VBYTES);       // [128][QS2]
    float* mrg = (float*)smem;                      // overlay [128][33] f32 after flash

    const int tid  = threadIdx.x;
    const int bid  = blockIdx.x;
    const int w    = bid & 511;            // window
    const int head = bid >> 9;
    const int cb   = head * 32;
    const int n    = w & 255;
    const int t    = w >> 8;

    const int r    = tid & 127;
    const int half = tid >> 7;
    const int qv_  = r >> 6, qtt = (r >> 4) & 3, qnn = (r >> 2) & 3, qdd = r & 3;
    const size_t qtok = ((size_t)(qv_ * 8 + t * 4 + qtt) * 1024 + n * 4 + qnn) * 4 + qdd;

    // ---- staging: threads 0-191 project the 192 real kv rows (LN once each).
    if (tid < NKV) {
        const int v_ = (tid >= 96) ? 1 : 0;
        const int rem = tid - v_ * 96;
        const int t2i = rem >> 4, nn = (rem >> 2) & 3, dd = rem & 3;
        const int t2 = t2i + (t == 0 ? 2 : 0);     // in-range t2 values only
        int tsrc, tt;
        if (t2 < 2)      { tsrc = t - 1; tt = t2 + 2; }
        else if (t2 < 6) { tsrc = t;     tt = t2 - 2; }
        else             { tsrc = t + 1; tt = t2 - 6; }
        f16x2 h2[32];
        const size_t tok = ((size_t)(v_ * 8 + tsrc * 4 + tt) * 1024 + n * 4 + nn) * 4 + dd;
        ln_row_f16(x + tok * 64, ln1_s, ln1_b, h2);
        #pragma unroll 1
        for (int which = 0; which < 2; ++which) {
            const int cbase = 128 * which + cb;
            #pragma unroll 1
            for (int chunk = 0; chunk < 2; ++chunk) {
                float acc[16];
                #pragma unroll
                for (int j = 0; j < 16; ++j) acc[j] = bkv[cbase + chunk * 16 + j];
                projh<16>(h2, Wkv + cbase + chunk * 16, 256, acc);
                if (which == 0) {
                    f16x8 p0, p1;
                    #pragma unroll
                    for (int j = 0; j < 8; ++j) { p0[j] = (f16)acc[j]; p1[j] = (f16)acc[j + 8]; }
                    ((f16x8*)(kl + tid * KS + chunk * 16))[0] = p0;
                    ((f16x8*)(kl + tid * KS + chunk * 16 + 8))[0] = p1;
                } else {
                    // pair-interleave: vl[pair][2*c + (tid&1)] = v[tid][c]
                    #pragma unroll
                    for (int j = 0; j < 16; ++j)
                        vl[(tid >> 1) * VSP + (chunk * 16 + j) * 2 + (tid & 1)] = (f16)acc[j];
                }
            }
        }
    }

    // ---- q half-projection (ALL threads): (r,half) computes channels [half*16, +16)
    {
        f16x2 h2q[32];
        ln_row_f16(x + qtok * 64, ln1_s, ln1_b, h2q);
        float qa[16];
        #pragma unroll
        for (int j = 0; j < 16; ++j) qa[j] = 0.f;   // q has no bias
        projh<16>(h2q, Wq + cb + half * 16, 128, qa);
        f16x8 p0, p1;
        #pragma unroll
        for (int j = 0; j < 8; ++j) { p0[j] = (f16)qa[j]; p1[j] = (f16)qa[j + 8]; }
        ((f16x8*)(ql + r * QS2 + half * 16))[0] = p0;
        ((f16x8*)(ql + r * QS2 + half * 16 + 8))[0] = p1;
    }
    __syncthreads();

    // ---- assemble q, analytic zero-row, flash over 48 kv pairs/half
    f16x2 q2[16];
    {
        const f16x8* qp = (const f16x8*)(ql + r * QS2);
        #pragma unroll
        for (int m = 0; m < 4; ++m) {
            const f16x8 qv = qp[m];
            #pragma unroll
            for (int i = 0; i < 4; ++i) q2[4*m + i] = (f16x2){qv[2*i], qv[2*i + 1]};
        }
    }

    float l = 0.f;
    float acc[32];
    #pragma unroll
    for (int j = 0; j < 32; ++j) acc[j] = 0.f;

    if (half == 0) {  // 320 zero tokens (depth halo + OOR time halo): k=bkv_k, v=bkv_v
        float sz = 0.f;
        #pragma unroll
        for (int j = 0; j < 16; ++j)
            sz += (float)q2[j].x * bkv[cb + 2*j] + (float)q2[j].y * bkv[cb + 2*j + 1];
        const float pz = exp2fast(fmaf(sz, C1, CZV));
        l = pz;
        #pragma unroll
        for (int j = 0; j < 32; ++j) acc[j] = pz * bkv[128 + cb + j];
    }

    const int pbase = half * (NVP / 2);
    #pragma unroll 2
    for (int p = pbase; p < pbase + (NVP / 2); ++p) {
        const f16x8* k0 = (const f16x8*)(kl + (2 * p) * KS);
        const f16x8* k1 = (const f16x8*)(kl + (2 * p + 1) * KS);
        // 4 independent accumulation chains (chain depth 8) for ILP
        float s0a = 0.f, s0b = 0.f, s1a = 0.f, s1b = 0.f;
        #pragma unroll
        for (int m = 0; m < 4; ++m) {
            const f16x8 a = k0[m], b = k1[m];
            s0a = fdot2f(q2[4*m+0], (f16x2){a[0], a[1]}, s0a);
            s0a = fdot2f(q2[4*m+1], (f16x2){a[2], a[3]}, s0a);
            s0b = fdot2f(q2[4*m+2], (f16x2){a[4], a[5]}, s0b);
            s0b = fdot2f(q2[4*m+3], (f16x2){a[6], a[7]}, s0b);
            s1a = fdot2f(q2[4*m+0], (f16x2){b[0], b[1]}, s1a);
            s1a = fdot2f(q2[4*m+1], (f16x2){b[2], b[3]}, s1a);
            s1b = fdot2f(q2[4*m+2], (f16x2){b[4], b[5]}, s1b);
            s1b = fdot2f(q2[4*m+3], (f16x2){b[6], b[7]}, s1b);
        }
        const float e0 = exp2fast(fmaf(s0a + s0b, C1, CZN));
        const float e1 = exp2fast(fmaf(s1a + s1b, C1, CZN));
        l += e0 + e1;
        const f16x2 pk = (f16x2){(f16)e0, (f16)e1};
        const f16x8* vv = (const f16x8*)(vl + p * VSP);
        #pragma unroll
        for (int m = 0; m < 8; ++m) {
            const f16x8 wv = vv[m];
            acc[4*m+0] = fdot2f(pk, (f16x2){wv[0], wv[1]}, acc[4*m+0]);
            acc[4*m+1] = fdot2f(pk, (f16x2){wv[2], wv[3]}, acc[4*m+1]);
            acc[4*m+2] = fdot2f(pk, (f16x2){wv[4], wv[5]}, acc[4*m+2]);
            acc[4*m+3] = fdot2f(pk, (f16x2){wv[6], wv[7]}, acc[4*m+3]);
        }
    }

    __syncthreads();            // flash reads of kl/vl/ql complete
    if (half) {
        float* mr = mrg + r * 33;
        #pragma unroll
        for (int j = 0; j < 32; ++j) mr[j] = acc[j];
        mr[32] = l;
    }
    __syncthreads();
    if (!half) {
        const float* mr = mrg + r * 33;
        const float inv = 1.0f / (l + mr[32]);
        f16* op = o_out + qtok * 128 + cb;
        #pragma unroll
        for (int m = 0; m < 8; ++m) {
            f16x4 st;
            st.x = (f16)((acc[4*m+0] + mr[4*m+0]) * inv);
            st.y = (f16)((acc[4*m+1] + mr[4*m+1]) * inv);
            st.z = (f16)((acc[4*m+2] + mr[4*m+2]) * inv);
            st.w = (f16)((acc[4*m+3] + mr[4*m+3]) * inv);
            ((f16x4*)op)[m] = st;
        }
    }
}

// ---------------- Kernel 2: row-local epilogue, 32 tokens/block x 8 threads/token ----------
__global__ __launch_bounds__(256, 3) void k_epi(
    const float* __restrict__ x, const f16* __restrict__ o_in,
    const float* __restrict__ Wo, const float* __restrict__ bo, const float* __restrict__ gamma,
    const float* __restrict__ ln2_s, const float* __restrict__ ln2_b,
    const float* __restrict__ W1, const float* __restrict__ b1,
    const float* __restrict__ W2, const float* __restrict__ b2,
    const float* __restrict__ gm, float* __restrict__ out)
{
    constexpr int OLS = 132, H2S = 68, REDS = 17;
    __shared__ __align__(16) char smem[32 * OLS * 2 + 32 * H2S * 2 + 32 * REDS * 4]; // 14976 B
    f16* ol   = (f16*)smem;                         // [32][132]
    f16* h2l  = (f16*)(smem + 32 * OLS * 2);        // [32][68]
    float* red = (float*)(smem + 32 * OLS * 2 + 32 * H2S * 2); // [32][17]
    f16* hidl = ol;                                  // overlay (o dead after upd)

    const int tid = threadIdx.x;
    const int r = tid & 31, s = tid >> 5;           // token-in-block, 8-way channel split
    const int f0 = s * 8;
    const size_t tok = (size_t)blockIdx.x * 32 + r;

    {   // stage o rows: 16 f16 per thread (4x f16x4, 8B aligned)
        const f16x4* src = (const f16x4*)(o_in + tok * 128 + s * 16);
        f16x4* dst = (f16x4*)(ol + r * OLS + s * 16);
        #pragma unroll
        for (int m = 0; m < 4; ++m) dst[m] = src[m];
    }
    __syncthreads();

    float upd[8];
    #pragma unroll
    for (int j = 0; j < 8; ++j) upd[j] = bo[f0 + j];
    {   // upd[f0..f0+8) = o_row @ Wo
        const f16x4* orow = (const f16x4*)(ol + r * OLS);
        #pragma unroll 8
        for (int m = 0; m < 32; ++m) {
            const f16x4 c4 = orow[m];
            const float c0 = (float)c4.x, c1 = (float)c4.y, c2 = (float)c4.z, c3 = (float)c4.w;
            const float* w0 = Wo + (4*m+0) * 64 + f0;
            const float* w1 = Wo + (4*m+1) * 64 + f0;
            const float* w2 = Wo + (4*m+2) * 64 + f0;
            const float* w3 = Wo + (4*m+3) * 64 + f0;
            #pragma unroll
            for (int j = 0; j < 8; ++j)
                upd[j] = fmaf(c0, w0[j], fmaf(c1, w1[j], fmaf(c2, w2[j], fmaf(c3, w3[j], upd[j]))));
        }
    }

    float tv[8]; float s1 = 0.f, s2 = 0.f;
    {   // residual; LN2 partial stats
        const float* xr = x + tok * 64 + f0;
        #pragma unroll
        for (int j = 0; j < 8; ++j) {
            const float tk = xr[j] + gamma[f0 + j] * upd[j];
            tv[j] = tk; s1 += tk; s2 += tk * tk;
        }
    }
    red[r * REDS + s * 2]     = s1;
    red[r * REDS + s * 2 + 1] = s2;
    __syncthreads();
    {   // LN2 finalize -> h2 (f16)
        float a1 = 0.f, a2 = 0.f;
        #pragma unroll
        for (int i = 0; i < 8; ++i) { a1 += red[r*REDS + 2*i]; a2 += red[r*REDS + 2*i + 1]; }
        const float mean = a1 * 0.015625f;
        const float var  = a2 * 0.015625f - mean * mean;
        const float rstd = rsqrtf(var + 1e-5f);
        #pragma unroll
        for (int j = 0; j < 8; ++j)
            h2l[r * H2S + f0 + j] = (f16)((tv[j] - mean) * rstd * ln2_s[f0 + j] + ln2_b[f0 + j]);
    }
    __syncthreads();
    {   // MLP1 + gelu(tanh) -> hid (f16, overlays o); 16 hidden ch per thread
        const int a0 = s * 16;
        float ha[16];
        #pragma unroll
        for (int j = 0; j < 16; ++j) ha[j] = b1[a0 + j];
        const f16x4* h2row = (const f16x4*)(h2l + r * H2S);
        #pragma unroll 8
        for (int m = 0; m < 16; ++m) {
            const f16x4 c4 = h2row[m];
            const float c0 = (float)c4.x, c1 = (float)c4.y, c2 = (float)c4.z, c3 = (float)c4.w;
            const float* w0 = W1 + (4*m+0) * 128 + a0;
            const float* w1 = W1 + (4*m+1) * 128 + a0;
            const float* w2 = W1 + (4*m+2) * 128 + a0;
            const float* w3 = W1 + (4*m+3) * 128 + a0;
            #pragma unroll
            for (int j = 0; j < 16; ++j)
                ha[j] = fmaf(c0, w0[j], fmaf(c1, w1[j], fmaf(c2, w2[j], fmaf(c3, w3[j], ha[j]))));
        }
        #pragma unroll
        for (int j = 0; j < 16; ++j) {
            const float z = ha[j];
            const float u = 0.7978845608028654f * (z + 0.044715f * z * z * z);
            hidl[r * OLS + a0 + j] = (f16)(0.5f * z * (1.0f + tanhf(u)));
        }
    }
    __syncthreads();
    {   // MLP2 + final residual -> out (f32, same bytes o came from)
        float oa[8];
        #pragma unroll
        for (int j = 0; j < 8; ++j) oa[j] = b2[f0 + j];
        const f16x4* hrow = (const f16x4*)(hidl + r * OLS);
        #pragma unroll 8
        for (int m = 0; m < 32; ++m) {
            const f16x4 c4 = hrow[m];
            const float c0 = (float)c4.x, c1 = (float)c4.y, c2 = (float)c4.z, c3 = (float)c4.w;
            const float* w0 = W2 + (4*m+0) * 64 + f0;
            const float* w1 = W2 + (4*m+1) * 64 + f0;
            const float* w2 = W2 + (4*m+2) * 64 + f0;
            const float* w3 = W2 + (4*m+3) * 64 + f0;
            #pragma unroll
            for (int j = 0; j < 8; ++j)
                oa[j] = fmaf(c0, w0[j], fmaf(c1, w1[j], fmaf(c2, w2[j], fmaf(c3, w3[j], oa[j]))));
        }
        float* orow = out + tok * 64 + f0;
        #pragma unroll
        for (int j = 0; j < 8; ++j) orow[j] = tv[j] + gm[f0 + j] * oa[j];
    }
}

extern "C" void kernel_launch(void* const* d_in, const int* in_sizes, int n_in,
                              void* d_out, int out_size, void* d_ws, size_t ws_size,
                              hipStream_t stream) {
    const float* x        = (const float*)d_in[0];
    const float* ln1_s    = (const float*)d_in[1];
    const float* ln1_b    = (const float*)d_in[2];
    const float* Wq       = (const float*)d_in[3];
    const float* Wkv      = (const float*)d_in[4];
    const float* bkv      = (const float*)d_in[5];
    const float* Wo       = (const float*)d_in[6];
    const float* bo       = (const float*)d_in[7];
    const float* gamma    = (const float*)d_in[8];
    const float* ln2_s    = (const float*)d_in[9];
    const float* ln2_b    = (const float*)d_in[10];
    const float* W1       = (const float*)d_in[11];
    const float* b1       = (const float*)d_in[12];
    const float* W2       = (const float*)d_in[13];
    const float* b2       = (const float*)d_in[14];
    const float* gamma_mlp= (const float*)d_in[15];

    // o (f16[65536][128]) aliases d_out (f32[65536][64]) — same 16.78 MB; tokens are
    // partitioned across windows so K_att writes and K_epi read/overwrite race-free.
    f16* o_buf = (f16*)d_out;
    float* out = (float*)d_out;

    hipLaunchKernelGGL(k_att, dim3(2048), dim3(256), 0, stream,
                       x, ln1_s, ln1_b, Wq, Wkv, bkv, o_buf);
    hipLaunchKernelGGL(k_epi, dim3(2048), dim3(256), 0, stream,
                       x, o_buf, Wo, bo, gamma, ln2_s, ln2_b, W1, b1, W2, b2, gamma_mlp, out);
}

// Round 10
// 245.523 us; speedup vs baseline: 1.4536x; 1.4536x over previous
//
#include <hip/hip_runtime.h>
#include <math.h>

typedef _Float16 f16;
typedef _Float16 f16x2 __attribute__((ext_vector_type(2)));
typedef _Float16 f16x4 __attribute__((ext_vector_type(4)));
typedef _Float16 f16x8 __attribute__((ext_vector_type(8)));

#if defined(__has_builtin)
#if __has_builtin(__builtin_amdgcn_fdot2)
#define USE_FDOT2 1
#endif
#if __has_builtin(__builtin_amdgcn_exp2f)
#define USE_EXP2 1
#endif
#endif

__device__ __forceinline__ float fdot2f(f16x2 a, f16x2 b, float c) {
#ifdef USE_FDOT2
    return __builtin_amdgcn_fdot2(a, b, c, false);
#else
    return c + (float)a.x * (float)b.x + (float)a.y * (float)b.y;
#endif
}
__device__ __forceinline__ float exp2fast(float a) {
#ifdef USE_EXP2
    return __builtin_amdgcn_exp2f(a);
#else
    return exp2f(a);
#endif
}

namespace {
// 192 real kv rows (V=2 x 6 in-range t2 x NN=4 x DD=4); 320 zero rows folded analytically.
constexpr int NKV = 192, NVP = 96;
constexpr int KS  = 40;                 // f16 per k row (32 data + 8 pad)
constexpr int VSP = 72;                 // f16 per v pair-row (64 data + 8 pad)
constexpr int KBYTES = NKV * KS * 2;    // 15360
constexpr int VBYTES = NVP * VSP * 2;   // 13824
constexpr float C1  = 0.2550600f;       // (1/sqrt(32)) * log2(e)
constexpr float CZN = -5.7707801f;      // -4*log2(e)  (fixed softmax shift, scores are tiny)
constexpr float CZV = 2.5511480f;       // CZN + log2(320): 320 identical zero-token kv rows

// packed-f16 weight buffer layout (f16x2 pair units): P[out][in/2], P[o][p]={W[2p][o],W[2p+1][o]}
constexpr int OFF_WQ  = 0;       // Wq  in64  out128 -> 4096 pairs, rows of 32
constexpr int OFF_WKV = 4096;    // Wkv in64  out256 -> 8192 pairs, rows of 32
constexpr int OFF_WO  = 12288;   // Wo  in128 out64  -> 4096 pairs, rows of 64
constexpr int OFF_W1  = 16384;   // W1  in64  out128 -> 4096 pairs, rows of 32
constexpr int OFF_W2  = 20480;   // W2  in128 out64  -> 4096 pairs, rows of 64
constexpr int NPAIRS  = 24576;   // 96 KB
}

__device__ f16x2 g_wpack[NPAIRS];

// ---------------- Kernel 0: pack all GEMV weights to f16x2 (deterministic each launch) ----
__global__ void k_conv(const float* __restrict__ Wq, const float* __restrict__ Wkv,
                       const float* __restrict__ Wo, const float* __restrict__ W1,
                       const float* __restrict__ W2) {
    const int i = blockIdx.x * 256 + threadIdx.x;   // pair index, grid covers NPAIRS exactly
    const float* src; int inp, out, base;
    if (i < OFF_WKV)     { src = Wq;  inp = 32; out = 128; base = OFF_WQ;  }
    else if (i < OFF_WO) { src = Wkv; inp = 32; out = 256; base = OFF_WKV; }
    else if (i < OFF_W1) { src = Wo;  inp = 64; out = 64;  base = OFF_WO;  }
    else if (i < OFF_W2) { src = W1;  inp = 32; out = 128; base = OFF_W1;  }
    else                 { src = W2;  inp = 64; out = 64;  base = OFF_W2;  }
    const int li = i - base;
    const int o = li / inp, p = li % inp;
    g_wpack[i] = (f16x2){(f16)src[(2*p) * out + o], (f16)src[(2*p+1) * out + o]};
}

// LayerNorm one 64-ch token row into PACKED f16x2[32] (32 VGPRs). All indices static.
__device__ __forceinline__ void ln_row_f16(const float* __restrict__ xrow,
                                           const float* __restrict__ ls,
                                           const float* __restrict__ lb,
                                           f16x2 h2[32]) {
    float s = 0.f, ss = 0.f;
    #pragma unroll
    for (int i = 0; i < 16; ++i) {
        const float4 t = ((const float4*)xrow)[i];
        s  += (t.x + t.y) + (t.z + t.w);
        ss += t.x*t.x + t.y*t.y + t.z*t.z + t.w*t.w;
        h2[2*i]   = (f16x2){(f16)t.x, (f16)t.y};
        h2[2*i+1] = (f16x2){(f16)t.z, (f16)t.w};
    }
    const float mean = s * 0.015625f;
    const float rstd = rsqrtf(ss * 0.015625f - mean*mean + 1e-5f);
    #pragma unroll
    for (int i = 0; i < 32; ++i) {
        const float a0 = ((float)h2[i].x - mean) * rstd * ls[2*i]   + lb[2*i];
        const float a1 = ((float)h2[i].y - mean) * rstd * ls[2*i+1] + lb[2*i+1];
        h2[i] = (f16x2){(f16)a0, (f16)a1};
    }
}

// acc[0..NACC) += h2 @ P (NACC rows of INP f16x2 pairs) via v_dot2_f32_f16.
// MUST be fully unrolled (rule #20: runtime index on h2[] -> scratch, 4x slowdown r3-r5).
template<int NACC, int INP>
__device__ __forceinline__ void projpk(const f16x2* __restrict__ h2,
                                       const f16x2* __restrict__ P,
                                       float* __restrict__ acc) {
    #pragma unroll
    for (int fp = 0; fp < INP; ++fp) {
        #pragma unroll
        for (int j = 0; j < NACC; ++j)
            acc[j] = fdot2f(h2[fp], P[j * INP + fp], acc[j]);
    }
}

// ---------------- Kernel 1: per-(window,head) attention, o -> d_out (f16) ----------------
// Structure = round-8 known-clean (q recomputed per flash thread; no q-LDS path).
__global__ __launch_bounds__(256, 3) void k_att(
    const float* __restrict__ x,
    const float* __restrict__ ln1_s, const float* __restrict__ ln1_b,
    const float* __restrict__ bkv,
    f16* __restrict__ o_out)
{
    __shared__ __align__(16) char smem[KBYTES + VBYTES];   // 29184 B
    f16* kl = (f16*)smem;                  // [192][KS]
    f16* vl = (f16*)(smem + KBYTES);       // [96 pairs][VSP]
    float* mrg = (float*)smem;             // overlay [128][33] f32 after flash (16896 B)

    const int tid  = threadIdx.x;
    const int bid  = blockIdx.x;
    const int w    = bid & 511;            // window
    const int head = bid >> 9;
    const int cb   = head * 32;
    const int n    = w & 255;
    const int t    = w >> 8;

    const f16x2* WqP  = g_wpack + OFF_WQ;
    const f16x2* WkvP = g_wpack + OFF_WKV;

    // ---- staging: threads 0-191 project the 192 real kv rows; wave 3 idles.
    if (tid < NKV) {
        const int v_ = (tid >= 96) ? 1 : 0;
        const int rem = tid - v_ * 96;
        const int t2i = rem >> 4, nn = (rem >> 2) & 3, dd = rem & 3;
        const int t2 = t2i + (t == 0 ? 2 : 0);     // in-range t2 values only
        int tsrc, tt;
        if (t2 < 2)      { tsrc = t - 1; tt = t2 + 2; }
        else if (t2 < 6) { tsrc = t;     tt = t2 - 2; }
        else             { tsrc = t + 1; tt = t2 - 6; }
        f16x2 h2[32];
        const size_t tok = ((size_t)(v_ * 8 + tsrc * 4 + tt) * 1024 + n * 4 + nn) * 4 + dd;
        ln_row_f16(x + tok * 64, ln1_s, ln1_b, h2);
        #pragma unroll 1
        for (int which = 0; which < 2; ++which) {
            #pragma unroll 1
            for (int chunk = 0; chunk < 2; ++chunk) {
                const int ob = which * 128 + cb + chunk * 16;   // out-channel base
                float acc[16];
                #pragma unroll
                for (int j = 0; j < 16; ++j) acc[j] = bkv[ob + j];
                projpk<16, 32>(h2, WkvP + ob * 32, acc);
                if (which == 0) {
                    f16x8 p0, p1;
                    #pragma unroll
                    for (int j = 0; j < 8; ++j) { p0[j] = (f16)acc[j]; p1[j] = (f16)acc[j + 8]; }
                    ((f16x8*)(kl + tid * KS + chunk * 16))[0] = p0;
                    ((f16x8*)(kl + tid * KS + chunk * 16 + 8))[0] = p1;
                } else {
                    // pair-interleave: vl[pair][2*c + (tid&1)] = v[tid][c]
                    #pragma unroll
                    for (int j = 0; j < 16; ++j)
                        vl[(tid >> 1) * VSP + (chunk * 16 + j) * 2 + (tid & 1)] = (f16)acc[j];
                }
            }
        }
    }
    __syncthreads();

    // ---- q projection (each half recomputes its row) + flash over 48 kv pairs/half
    const int r    = tid & 127;
    const int half = tid >> 7;
    const int v_   = r >> 6, tt = (r >> 4) & 3, nn = (r >> 2) & 3, dd = r & 3;
    const size_t qtok = ((size_t)(v_ * 8 + t * 4 + tt) * 1024 + n * 4 + nn) * 4 + dd;

    float l = 0.f;
    float acc[32];
    #pragma unroll
    for (int j = 0; j < 32; ++j) acc[j] = 0.f;
    f16x2 q2[16];
    {
        f16x2 h2[32];
        ln_row_f16(x + qtok * 64, ln1_s, ln1_b, h2);
        float qf[32];
        #pragma unroll
        for (int j = 0; j < 32; ++j) qf[j] = 0.f;
        projpk<16, 32>(h2, WqP + cb * 32, qf);
        projpk<16, 32>(h2, WqP + (cb + 16) * 32, qf + 16);

        if (half == 0) {  // 320 zero tokens (depth halo + OOR time halo): k=bkv_k, v=bkv_v
            float sz = 0.f;
            #pragma unroll
            for (int j = 0; j < 32; ++j) sz = fmaf(qf[j], bkv[cb + j], sz);
            const float pz = exp2fast(fmaf(sz, C1, CZV));
            l = pz;
            #pragma unroll
            for (int j = 0; j < 32; ++j) acc[j] = pz * bkv[128 + cb + j];
        }
        #pragma unroll
        for (int j = 0; j < 16; ++j) q2[j] = (f16x2){(f16)qf[2*j], (f16)qf[2*j+1]};
    }

    const int pbase = half * (NVP / 2);
    #pragma unroll 2
    for (int p = pbase; p < pbase + (NVP / 2); ++p) {
        const f16x8* k0 = (const f16x8*)(kl + (2 * p) * KS);
        const f16x8* k1 = (const f16x8*)(kl + (2 * p + 1) * KS);
        // 4 independent accumulation chains (chain depth 8) for ILP
        float s0a = 0.f, s0b = 0.f, s1a = 0.f, s1b = 0.f;
        #pragma unroll
        for (int m = 0; m < 4; ++m) {
            const f16x8 a = k0[m], b = k1[m];
            s0a = fdot2f(q2[4*m+0], (f16x2){a[0], a[1]}, s0a);
            s0a = fdot2f(q2[4*m+1], (f16x2){a[2], a[3]}, s0a);
            s0b = fdot2f(q2[4*m+2], (f16x2){a[4], a[5]}, s0b);
            s0b = fdot2f(q2[4*m+3], (f16x2){a[6], a[7]}, s0b);
            s1a = fdot2f(q2[4*m+0], (f16x2){b[0], b[1]}, s1a);
            s1a = fdot2f(q2[4*m+1], (f16x2){b[2], b[3]}, s1a);
            s1b = fdot2f(q2[4*m+2], (f16x2){b[4], b[5]}, s1b);
            s1b = fdot2f(q2[4*m+3], (f16x2){b[6], b[7]}, s1b);
        }
        const float e0 = exp2fast(fmaf(s0a + s0b, C1, CZN));
        const float e1 = exp2fast(fmaf(s1a + s1b, C1, CZN));
        l += e0 + e1;
        const f16x2 pk = (f16x2){(f16)e0, (f16)e1};
        const f16x8* vv = (const f16x8*)(vl + p * VSP);
        #pragma unroll
        for (int m = 0; m < 8; ++m) {
            const f16x8 wv = vv[m];
            acc[4*m+0] = fdot2f(pk, (f16x2){wv[0], wv[1]}, acc[4*m+0]);
            acc[4*m+1] = fdot2f(pk, (f16x2){wv[2], wv[3]}, acc[4*m+1]);
            acc[4*m+2] = fdot2f(pk, (f16x2){wv[4], wv[5]}, acc[4*m+2]);
            acc[4*m+3] = fdot2f(pk, (f16x2){wv[6], wv[7]}, acc[4*m+3]);
        }
    }

    __syncthreads();            // flash reads of kl/vl complete
    if (half) {
        float* mr = mrg + r * 33;
        #pragma unroll
        for (int j = 0; j < 32; ++j) mr[j] = acc[j];
        mr[32] = l;
    }
    __syncthreads();
    if (!half) {
        const float* mr = mrg + r * 33;
        const float inv = 1.0f / (l + mr[32]);
        f16* op = o_out + qtok * 128 + cb;
        #pragma unroll
        for (int m = 0; m < 8; ++m) {
            f16x4 st;
            st.x = (f16)((acc[4*m+0] + mr[4*m+0]) * inv);
            st.y = (f16)((acc[4*m+1] + mr[4*m+1]) * inv);
            st.z = (f16)((acc[4*m+2] + mr[4*m+2]) * inv);
            st.w = (f16)((acc[4*m+3] + mr[4*m+3]) * inv);
            ((f16x4*)op)[m] = st;
        }
    }
}

// ---------------- Kernel 2: row-local epilogue, 32 tokens/block x 8 threads/token ----------
__global__ __launch_bounds__(256, 3) void k_epi(
    const float* __restrict__ x, const f16* __restrict__ o_in,
    const float* __restrict__ bo, const float* __restrict__ gamma,
    const float* __restrict__ ln2_s, const float* __restrict__ ln2_b,
    const float* __restrict__ b1, const float* __restrict__ b2,
    const float* __restrict__ gm, float* __restrict__ out)
{
    constexpr int OLS = 132, H2S = 68, REDS = 17;
    __shared__ __align__(16) char smem[32 * OLS * 2 + 32 * H2S * 2 + 32 * REDS * 4]; // 14976 B
    f16* ol   = (f16*)smem;                         // [32][132]
    f16* h2l  = (f16*)(smem + 32 * OLS * 2);        // [32][68]
    float* red = (float*)(smem + 32 * OLS * 2 + 32 * H2S * 2); // [32][17]
    f16* hidl = ol;                                  // overlay (o dead after upd)

    const f16x2* WoP = g_wpack + OFF_WO;   // [64][64]
    const f16x2* W1P = g_wpack + OFF_W1;   // [128][32]
    const f16x2* W2P = g_wpack + OFF_W2;   // [64][64]

    const int tid = threadIdx.x;
    const int r = tid & 31, s = tid >> 5;           // token-in-block, 8-way channel split
    const int f0 = s * 8;
    const size_t tok = (size_t)blockIdx.x * 32 + r;

    {   // stage o rows: 16 f16 per thread (4x f16x4, 8B aligned)
        const f16x4* src = (const f16x4*)(o_in + tok * 128 + s * 16);
        f16x4* dst = (f16x4*)(ol + r * OLS + s * 16);
        #pragma unroll
        for (int m = 0; m < 4; ++m) dst[m] = src[m];
    }
    __syncthreads();

    float upd[8];
    #pragma unroll
    for (int j = 0; j < 8; ++j) upd[j] = bo[f0 + j];
    {   // upd[f0..f0+8) = o_row(128) @ Wo
        const f16x4* orow = (const f16x4*)(ol + r * OLS);
        #pragma unroll 8
        for (int m = 0; m < 32; ++m) {
            const f16x4 c4 = orow[m];
            const f16x2 p0 = (f16x2){c4.x, c4.y}, p1 = (f16x2){c4.z, c4.w};
            #pragma unroll
            for (int j = 0; j < 8; ++j)
                upd[j] = fdot2f(p1, WoP[(f0+j)*64 + 2*m + 1], fdot2f(p0, WoP[(f0+j)*64 + 2*m], upd[j]));
        }
    }

    float tv[8]; float s1 = 0.f, s2 = 0.f;
    {   // residual; LN2 partial stats
        const float* xr = x + tok * 64 + f0;
        #pragma unroll
        for (int j = 0; j < 8; ++j) {
            const float tk = xr[j] + gamma[f0 + j] * upd[j];
            tv[j] = tk; s1 += tk; s2 += tk * tk;
        }
    }
    red[r * REDS + s * 2]     = s1;
    red[r * REDS + s * 2 + 1] = s2;
    __syncthreads();
    {   // LN2 finalize -> h2 (f16)
        float a1 = 0.f, a2 = 0.f;
        #pragma unroll
        for (int i = 0; i < 8; ++i) { a1 += red[r*REDS + 2*i]; a2 += red[r*REDS + 2*i + 1]; }
        const float mean = a1 * 0.015625f;
        const float var  = a2 * 0.015625f - mean * mean;
        const float rstd = rsqrtf(var + 1e-5f);
        #pragma unroll
        for (int j = 0; j < 8; ++j)
            h2l[r * H2S + f0 + j] = (f16)((tv[j] - mean) * rstd * ln2_s[f0 + j] + ln2_b[f0 + j]);
    }
    __syncthreads();
    {   // MLP1 + gelu(tanh) -> hid (f16, overlays o); 16 hidden ch per thread
        const int a0 = s * 16;
        float ha[16];
        #pragma unroll
        for (int j = 0; j < 16; ++j) ha[j] = b1[a0 + j];
        const f16x4* h2row = (const f16x4*)(h2l + r * H2S);
        #pragma unroll 8
        for (int m = 0; m < 16; ++m) {
            const f16x4 c4 = h2row[m];
            const f16x2 p0 = (f16x2){c4.x, c4.y}, p1 = (f16x2){c4.z, c4.w};
            #pragma unroll
            for (int j = 0; j < 16; ++j)
                ha[j] = fdot2f(p1, W1P[(a0+j)*32 + 2*m + 1], fdot2f(p0, W1P[(a0+j)*32 + 2*m], ha[j]));
        }
        #pragma unroll
        for (int j = 0; j < 16; ++j) {
            const float z = ha[j];
            const float u = 0.7978845608028654f * (z + 0.044715f * z * z * z);
            hidl[r * OLS + a0 + j] = (f16)(0.5f * z * (1.0f + tanhf(u)));
        }
    }
    __syncthreads();
    {   // MLP2 + final residual -> out (f32, same bytes o came from)
        float oa[8];
        #pragma unroll
        for (int j = 0; j < 8; ++j) oa[j] = b2[f0 + j];
        const f16x4* hrow = (const f16x4*)(hidl + r * OLS);
        #pragma unroll 8
        for (int m = 0; m < 32; ++m) {
            const f16x4 c4 = hrow[m];
            const f16x2 p0 = (f16x2){c4.x, c4.y}, p1 = (f16x2){c4.z, c4.w};
            #pragma unroll
            for (int j = 0; j < 8; ++j)
                oa[j] = fdot2f(p1, W2P[(f0+j)*64 + 2*m + 1], fdot2f(p0, W2P[(f0+j)*64 + 2*m], oa[j]));
        }
        float* orow = out + tok * 64 + f0;
        #pragma unroll
        for (int j = 0; j < 8; ++j) orow[j] = tv[j] + gm[f0 + j] * oa[j];
    }
}

extern "C" void kernel_launch(void* const* d_in, const int* in_sizes, int n_in,
                              void* d_out, int out_size, void* d_ws, size_t ws_size,
                              hipStream_t stream) {
    const float* x        = (const float*)d_in[0];
    const float* ln1_s    = (const float*)d_in[1];
    const float* ln1_b    = (const float*)d_in[2];
    const float* Wq       = (const float*)d_in[3];
    const float* Wkv      = (const float*)d_in[4];
    const float* bkv      = (const float*)d_in[5];
    const float* Wo       = (const float*)d_in[6];
    const float* bo       = (const float*)d_in[7];
    const float* gamma    = (const float*)d_in[8];
    const float* ln2_s    = (const float*)d_in[9];
    const float* ln2_b    = (const float*)d_in[10];
    const float* W1       = (const float*)d_in[11];
    const float* b1       = (const float*)d_in[12];
    const float* W2       = (const float*)d_in[13];
    const float* b2       = (const float*)d_in[14];
    const float* gamma_mlp= (const float*)d_in[15];

    // o (f16[65536][128]) aliases d_out (f32[65536][64]) — same 16.78 MB; tokens are
    // partitioned across windows so K_att writes and K_epi read/overwrite race-free.
    f16* o_buf = (f16*)d_out;
    float* out = (float*)d_out;

    hipLaunchKernelGGL(k_conv, dim3(NPAIRS / 256), dim3(256), 0, stream,
                       Wq, Wkv, Wo, W1, W2);
    hipLaunchKernelGGL(k_att, dim3(2048), dim3(256), 0, stream,
                       x, ln1_s, ln1_b, bkv, o_buf);
    hipLaunchKernelGGL(k_epi, dim3(2048), dim3(256), 0, stream,
                       x, o_buf, bo, gamma, ln2_s, ln2_b, b1, b2, gamma_mlp, out);
}

// Round 12
// 234.295 us; speedup vs baseline: 1.5232x; 1.0479x over previous
//
#include <hip/hip_runtime.h>
#include <math.h>

typedef _Float16 f16;
typedef _Float16 f16x2 __attribute__((ext_vector_type(2)));
typedef _Float16 f16x4 __attribute__((ext_vector_type(4)));
typedef _Float16 f16x8 __attribute__((ext_vector_type(8)));
typedef float f32x4 __attribute__((ext_vector_type(4)));

#if defined(__has_builtin)
#if __has_builtin(__builtin_amdgcn_fdot2)
#define USE_FDOT2 1
#endif
#if __has_builtin(__builtin_amdgcn_exp2f)
#define USE_EXP2 1
#endif
#endif

__device__ __forceinline__ float fdot2f(f16x2 a, f16x2 b, float c) {
#ifdef USE_FDOT2
    return __builtin_amdgcn_fdot2(a, b, c, false);
#else
    return c + (float)a.x * (float)b.x + (float)a.y * (float)b.y;
#endif
}
__device__ __forceinline__ float exp2fast(float a) {
#ifdef USE_EXP2
    return __builtin_amdgcn_exp2f(a);
#else
    return exp2f(a);
#endif
}

namespace {
// 192 real kv rows; 320 zero rows folded analytically (pz, multiplicity 320).
constexpr int NKV = 192;
constexpr int KS  = 40;    // f16/row k LDS
constexpr int QLS = 40;    // f16/row q LDS
constexpr int VTS = 200;   // f16/row of V-transposed [32 ch][192 kv + pad]
constexpr int PS  = 104;   // f16/row of P [128][96 + pad]
constexpr int OFF_KL = 0;            // 192*40*2  = 15360
constexpr int OFF_VT = 15360;        // 32*200*2  = 12800
constexpr int OFF_QL = 28160;        // 128*40*2  = 10240
constexpr int OFF_P  = 38400;        // 128*104*2 = 26624
constexpr int OFF_LI = 65024;        // f32[128]
constexpr int OFF_PZ = 65536;        // f32[128]
constexpr int ATT_LDS = 66048;       // -> 2 blocks/CU
constexpr float C1  = 0.2550600f;    // (1/sqrt(32)) * log2(e)
constexpr float CZN = -5.7707801f;   // -4*log2(e)  (fixed softmax shift; scores tiny)
constexpr float CZV = 2.5511480f;    // CZN + log2(320)

// packed-f16 weights: P[out][in/2] f16x2 pairs
constexpr int OFF_WQ  = 0;
constexpr int OFF_WKV = 4096;
constexpr int OFF_WO  = 12288;
constexpr int OFF_W1  = 16384;
constexpr int OFF_W2  = 20480;
constexpr int NPAIRS  = 24576;
}

__device__ f16x2 g_wpack[NPAIRS];

// ---------------- Kernel 0: pack GEMV weights to f16x2 ----------------
__global__ void k_conv(const float* __restrict__ Wq, const float* __restrict__ Wkv,
                       const float* __restrict__ Wo, const float* __restrict__ W1,
                       const float* __restrict__ W2) {
    const int i = blockIdx.x * 256 + threadIdx.x;
    const float* src; int inp, out, base;
    if (i < OFF_WKV)     { src = Wq;  inp = 32; out = 128; base = OFF_WQ;  }
    else if (i < OFF_WO) { src = Wkv; inp = 32; out = 256; base = OFF_WKV; }
    else if (i < OFF_W1) { src = Wo;  inp = 64; out = 64;  base = OFF_WO;  }
    else if (i < OFF_W2) { src = W1;  inp = 32; out = 128; base = OFF_W1;  }
    else                 { src = W2;  inp = 64; out = 64;  base = OFF_W2;  }
    const int li = i - base;
    const int o = li / inp, p = li % inp;
    g_wpack[i] = (f16x2){(f16)src[(2*p) * out + o], (f16)src[(2*p+1) * out + o]};
}

// LayerNorm one 64-ch row into PACKED f16x2[32]. All indices static (rule #20).
__device__ __forceinline__ void ln_row_f16(const float* __restrict__ xrow,
                                           const float* __restrict__ ls,
                                           const float* __restrict__ lb,
                                           f16x2 h2[32]) {
    float s = 0.f, ss = 0.f;
    #pragma unroll
    for (int i = 0; i < 16; ++i) {
        const float4 t = ((const float4*)xrow)[i];
        s  += (t.x + t.y) + (t.z + t.w);
        ss += t.x*t.x + t.y*t.y + t.z*t.z + t.w*t.w;
        h2[2*i]   = (f16x2){(f16)t.x, (f16)t.y};
        h2[2*i+1] = (f16x2){(f16)t.z, (f16)t.w};
    }
    const float mean = s * 0.015625f;
    const float rstd = rsqrtf(ss * 0.015625f - mean*mean + 1e-5f);
    #pragma unroll
    for (int i = 0; i < 32; ++i) {
        const float a0 = ((float)h2[i].x - mean) * rstd * ls[2*i]   + lb[2*i];
        const float a1 = ((float)h2[i].y - mean) * rstd * ls[2*i+1] + lb[2*i+1];
        h2[i] = (f16x2){(f16)a0, (f16)a1};
    }
}

// acc[0..NACC) += h2 @ P via v_dot2_f32_f16. MUST stay fully unrolled (rule #20).
template<int NACC, int INP>
__device__ __forceinline__ void projpk(const f16x2* __restrict__ h2,
                                       const f16x2* __restrict__ P,
                                       float* __restrict__ acc) {
    #pragma unroll
    for (int fp = 0; fp < INP; ++fp) {
        #pragma unroll
        for (int j = 0; j < NACC; ++j)
            acc[j] = fdot2f(h2[fp], P[j * INP + fp], acc[j]);
    }
}

// ---------------- Kernel 1: per-(window,head) attention via MFMA ----------------
__global__ __launch_bounds__(256, 2) void k_att(
    const float* __restrict__ x,
    const float* __restrict__ ln1_s, const float* __restrict__ ln1_b,
    const float* __restrict__ bkv,
    f16* __restrict__ o_out)
{
    __shared__ __align__(16) char smem[ATT_LDS];
    f16* kl   = (f16*)(smem + OFF_KL);
    f16* vt   = (f16*)(smem + OFF_VT);
    f16* ql   = (f16*)(smem + OFF_QL);
    f16* Pl   = (f16*)(smem + OFF_P);
    float* linv = (float*)(smem + OFF_LI);
    float* pzn  = (float*)(smem + OFF_PZ);

    const int tid  = threadIdx.x;
    const int bid  = blockIdx.x;
    const int w    = bid & 511;
    const int head = bid >> 9;
    const int cb   = head * 32;
    const int n    = w & 255;
    const int t    = w >> 8;

    const f16x2* WqP  = g_wpack + OFF_WQ;
    const f16x2* WkvP = g_wpack + OFF_WKV;

    // ---- staging (threads 0-191): kv rows -> kl / vt(transposed); own rows also -> ql
    if (tid < NKV) {
        const int v_ = (tid >= 96) ? 1 : 0;
        const int rem = tid - v_ * 96;
        const int t2i = rem >> 4, nn = (rem >> 2) & 3, dd = rem & 3;
        const int t2 = t2i + (t == 0 ? 2 : 0);
        int tsrc, tt;
        if (t2 < 2)      { tsrc = t - 1; tt = t2 + 2; }
        else if (t2 < 6) { tsrc = t;     tt = t2 - 2; }
        else             { tsrc = t + 1; tt = t2 - 6; }
        f16x2 h2[32];
        const size_t tok = ((size_t)(v_ * 8 + tsrc * 4 + tt) * 1024 + n * 4 + nn) * 4 + dd;
        ln_row_f16(x + tok * 64, ln1_s, ln1_b, h2);
        #pragma unroll 1
        for (int which = 0; which < 2; ++which) {
            #pragma unroll 1
            for (int chunk = 0; chunk < 2; ++chunk) {
                const int ob = which * 128 + cb + chunk * 16;
                float acc[16];
                #pragma unroll
                for (int j = 0; j < 16; ++j) acc[j] = bkv[ob + j];
                projpk<16, 32>(h2, WkvP + ob * 32, acc);
                if (which == 0) {
                    f16x8 p0, p1;
                    #pragma unroll
                    for (int j = 0; j < 8; ++j) { p0[j] = (f16)acc[j]; p1[j] = (f16)acc[j + 8]; }
                    ((f16x8*)(kl + tid * KS + chunk * 16))[0] = p0;
                    ((f16x8*)(kl + tid * KS + chunk * 16 + 8))[0] = p1;
                } else {
                    // V transposed: vt[ch][kvrow]
                    #pragma unroll
                    for (int j = 0; j < 16; ++j)
                        vt[(chunk * 16 + j) * VTS + tid] = (f16)acc[j];
                }
            }
        }
        if (tsrc == t) {   // this kv row IS one of the window's 128 q tokens: project q too
            const int qr = v_ * 64 + tt * 16 + nn * 4 + dd;
            float q0[16], q1[16];
            #pragma unroll
            for (int j = 0; j < 16; ++j) { q0[j] = 0.f; q1[j] = 0.f; }
            projpk<16, 32>(h2, WqP + cb * 32, q0);
            projpk<16, 32>(h2, WqP + (cb + 16) * 32, q1);
            // r11 bug fixed: store all four 8-lane chunks at 0/8/16/24 (ch 24-31 were
            // previously never written -> uninitialized LDS -> NaN).
            f16x8 pa, pb, pc, pd;
            #pragma unroll
            for (int j = 0; j < 8; ++j) {
                pa[j] = (f16)q0[j];     pb[j] = (f16)q0[j + 8];
                pc[j] = (f16)q1[j];     pd[j] = (f16)q1[j + 8];
            }
            ((f16x8*)(ql + qr * QLS +  0))[0] = pa;
            ((f16x8*)(ql + qr * QLS +  8))[0] = pb;
            ((f16x8*)(ql + qr * QLS + 16))[0] = pc;
            ((f16x8*)(ql + qr * QLS + 24))[0] = pd;
        }
    }
    __syncthreads();

    const int lane = tid & 63, wv = tid >> 6;
    const int lr = lane & 15, lg = lane >> 4;
    const int mA = wv * 32;          // this wave's PV m-base (rows mA..mA+31)

    // per-row virtual zero-token weight (threads 0-127, one per q row)
    float pz = 0.f, l_acc = 0.f;
    if (tid < 128) {
        const f16x2* qr2 = (const f16x2*)(ql + tid * QLS);
        float sz = 0.f;
        #pragma unroll
        for (int j = 0; j < 16; ++j)
            sz += (float)qr2[j].x * bkv[cb + 2*j] + (float)qr2[j].y * bkv[cb + 2*j + 1];
        pz = exp2fast(fmaf(sz, C1, CZV));
    }

    f32x4 oc00 = {0.f,0.f,0.f,0.f}, oc01 = {0.f,0.f,0.f,0.f};
    f32x4 oc10 = {0.f,0.f,0.f,0.f}, oc11 = {0.f,0.f,0.f,0.f};

    #pragma unroll 1
    for (int h = 0; h < 2; ++h) {
        // QK^T: 48 tiles (8M x 6N), 12 per wave; K=32 in one MFMA
        #pragma unroll 2
        for (int i = 0; i < 12; ++i) {
            const int tq = wv * 12 + i;
            const int m0 = (tq / 6) * 16;
            const int nl = (tq % 6) * 16;
            const f16x8 af = *(const f16x8*)(ql + (m0 + lr) * QLS + lg * 8);
            const f16x8 bf = *(const f16x8*)(kl + (h * 96 + nl + lr) * KS + lg * 8);
            const f32x4 c = __builtin_amdgcn_mfma_f32_16x16x32_f16(af, bf, (f32x4){0.f,0.f,0.f,0.f}, 0, 0, 0);
            #pragma unroll
            for (int e = 0; e < 4; ++e)
                Pl[(m0 + lg * 4 + e) * PS + nl + lr] = (f16)exp2fast(fmaf(c[e], C1, CZN));
        }
        __syncthreads();   // P ready

        // PV: this wave's 2 m-tiles x 2 n-tiles, K=96 in 3 steps
        #pragma unroll
        for (int kk = 0; kk < 3; ++kk) {
            const f16x8 a0 = *(const f16x8*)(Pl + (mA + lr) * PS + kk * 32 + lg * 8);
            const f16x8 a1 = *(const f16x8*)(Pl + (mA + 16 + lr) * PS + kk * 32 + lg * 8);
            const f16x8 b0 = *(const f16x8*)(vt + lr * VTS + h * 96 + kk * 32 + lg * 8);
            const f16x8 b1 = *(const f16x8*)(vt + (16 + lr) * VTS + h * 96 + kk * 32 + lg * 8);
            oc00 = __builtin_amdgcn_mfma_f32_16x16x32_f16(a0, b0, oc00, 0, 0, 0);
            oc01 = __builtin_amdgcn_mfma_f32_16x16x32_f16(a0, b1, oc01, 0, 0, 0);
            oc10 = __builtin_amdgcn_mfma_f32_16x16x32_f16(a1, b0, oc10, 0, 0, 0);
            oc11 = __builtin_amdgcn_mfma_f32_16x16x32_f16(a1, b1, oc11, 0, 0, 0);
        }
        // l partial: row sum of P (this half)
        if (tid < 128) {
            const f16x2* pr = (const f16x2*)(Pl + tid * PS);
            const f16x2 ones = (f16x2){(f16)1.f, (f16)1.f};
            float sa = 0.f, sb = 0.f;
            #pragma unroll
            for (int j = 0; j < 24; ++j) { sa = fdot2f(pr[2*j], ones, sa); sb = fdot2f(pr[2*j+1], ones, sb); }
            l_acc += sa + sb;
        }
        __syncthreads();   // P fully consumed; next half may overwrite
    }

    if (tid < 128) {
        const float inv = 1.0f / (l_acc + pz);
        linv[tid] = inv;
        pzn[tid]  = pz * inv;
    }
    __syncthreads();

    // epilogue: O = C*linv[row] + pzn[row]*bkv_v[col], f16 store
    #define EPI_TILE(CC, MI, NI) { \
        const int ch = (NI) * 16 + lr; \
        const float bv = bkv[128 + cb + ch]; \
        _Pragma("unroll") \
        for (int e = 0; e < 4; ++e) { \
            const int row = mA + (MI) * 16 + lg * 4 + e; \
            const float oo = fmaf(pzn[row], bv, CC[e] * linv[row]); \
            const int v2 = row >> 6, tt2 = (row >> 4) & 3, nn2 = (row >> 2) & 3, dd2 = row & 3; \
            const size_t tk = ((size_t)(v2 * 8 + t * 4 + tt2) * 1024 + n * 4 + nn2) * 4 + dd2; \
            o_out[tk * 128 + cb + ch] = (f16)oo; \
        } }
    EPI_TILE(oc00, 0, 0)
    EPI_TILE(oc01, 0, 1)
    EPI_TILE(oc10, 1, 0)
    EPI_TILE(oc11, 1, 1)
    #undef EPI_TILE
}

// ---------------- Kernel 2: row-local epilogue, 32 tokens/block x 8 threads/token ----------
__global__ __launch_bounds__(256, 3) void k_epi(
    const float* __restrict__ x, const f16* __restrict__ o_in,
    const float* __restrict__ bo, const float* __restrict__ gamma,
    const float* __restrict__ ln2_s, const float* __restrict__ ln2_b,
    const float* __restrict__ b1, const float* __restrict__ b2,
    const float* __restrict__ gm, float* __restrict__ out)
{
    constexpr int OLS = 132, H2S = 68, REDS = 17;
    __shared__ __align__(16) char smem[32 * OLS * 2 + 32 * H2S * 2 + 32 * REDS * 4]; // 14976 B
    f16* ol   = (f16*)smem;
    f16* h2l  = (f16*)(smem + 32 * OLS * 2);
    float* red = (float*)(smem + 32 * OLS * 2 + 32 * H2S * 2);
    f16* hidl = ol;

    const f16x2* WoP = g_wpack + OFF_WO;
    const f16x2* W1P = g_wpack + OFF_W1;
    const f16x2* W2P = g_wpack + OFF_W2;

    const int tid = threadIdx.x;
    const int r = tid & 31, s = tid >> 5;
    const int f0 = s * 8;
    const size_t tok = (size_t)blockIdx.x * 32 + r;

    {
        const f16x4* src = (const f16x4*)(o_in + tok * 128 + s * 16);
        f16x4* dst = (f16x4*)(ol + r * OLS + s * 16);
        #pragma unroll
        for (int m = 0; m < 4; ++m) dst[m] = src[m];
    }
    __syncthreads();

    float upd[8];
    #pragma unroll
    for (int j = 0; j < 8; ++j) upd[j] = bo[f0 + j];
    {
        const f16x4* orow = (const f16x4*)(ol + r * OLS);
        #pragma unroll 8
        for (int m = 0; m < 32; ++m) {
            const f16x4 c4 = orow[m];
            const f16x2 p0 = (f16x2){c4.x, c4.y}, p1 = (f16x2){c4.z, c4.w};
            #pragma unroll
            for (int j = 0; j < 8; ++j)
                upd[j] = fdot2f(p1, WoP[(f0+j)*64 + 2*m + 1], fdot2f(p0, WoP[(f0+j)*64 + 2*m], upd[j]));
        }
    }

    float tv[8]; float s1 = 0.f, s2 = 0.f;
    {
        const float* xr = x + tok * 64 + f0;
        #pragma unroll
        for (int j = 0; j < 8; ++j) {
            const float tk = xr[j] + gamma[f0 + j] * upd[j];
            tv[j] = tk; s1 += tk; s2 += tk * tk;
        }
    }
    red[r * REDS + s * 2]     = s1;
    red[r * REDS + s * 2 + 1] = s2;
    __syncthreads();
    {
        float a1 = 0.f, a2 = 0.f;
        #pragma unroll
        for (int i = 0; i < 8; ++i) { a1 += red[r*REDS + 2*i]; a2 += red[r*REDS + 2*i + 1]; }
        const float mean = a1 * 0.015625f;
        const float var  = a2 * 0.015625f - mean * mean;
        const float rstd = rsqrtf(var + 1e-5f);
        #pragma unroll
        for (int j = 0; j < 8; ++j)
            h2l[r * H2S + f0 + j] = (f16)((tv[j] - mean) * rstd * ln2_s[f0 + j] + ln2_b[f0 + j]);
    }
    __syncthreads();
    {
        const int a0 = s * 16;
        float ha[16];
        #pragma unroll
        for (int j = 0; j < 16; ++j) ha[j] = b1[a0 + j];
        const f16x4* h2row = (const f16x4*)(h2l + r * H2S);
        #pragma unroll 8
        for (int m = 0; m < 16; ++m) {
            const f16x4 c4 = h2row[m];
            const f16x2 p0 = (f16x2){c4.x, c4.y}, p1 = (f16x2){c4.z, c4.w};
            #pragma unroll
            for (int j = 0; j < 16; ++j)
                ha[j] = fdot2f(p1, W1P[(a0+j)*32 + 2*m + 1], fdot2f(p0, W1P[(a0+j)*32 + 2*m], ha[j]));
        }
        #pragma unroll
        for (int j = 0; j < 16; ++j) {
            const float z = ha[j];
            const float u = 0.7978845608028654f * (z + 0.044715f * z * z * z);
            hidl[r * OLS + a0 + j] = (f16)(0.5f * z * (1.0f + tanhf(u)));
        }
    }
    __syncthreads();
    {
        float oa[8];
        #pragma unroll
        for (int j = 0; j < 8; ++j) oa[j] = b2[f0 + j];
        const f16x4* hrow = (const f16x4*)(hidl + r * OLS);
        #pragma unroll 8
        for (int m = 0; m < 32; ++m) {
            const f16x4 c4 = hrow[m];
            const f16x2 p0 = (f16x2){c4.x, c4.y}, p1 = (f16x2){c4.z, c4.w};
            #pragma unroll
            for (int j = 0; j < 8; ++j)
                oa[j] = fdot2f(p1, W2P[(f0+j)*64 + 2*m + 1], fdot2f(p0, W2P[(f0+j)*64 + 2*m], oa[j]));
        }
        float* orow = out + tok * 64 + f0;
        #pragma unroll
        for (int j = 0; j < 8; ++j) orow[j] = tv[j] + gm[f0 + j] * oa[j];
    }
}

extern "C" void kernel_launch(void* const* d_in, const int* in_sizes, int n_in,
                              void* d_out, int out_size, void* d_ws, size_t ws_size,
                              hipStream_t stream) {
    const float* x        = (const float*)d_in[0];
    const float* ln1_s    = (const float*)d_in[1];
    const float* ln1_b    = (const float*)d_in[2];
    const float* Wq       = (const float*)d_in[3];
    const float* Wkv      = (const float*)d_in[4];
    const float* bkv      = (const float*)d_in[5];
    const float* Wo       = (const float*)d_in[6];
    const float* bo       = (const float*)d_in[7];
    const float* gamma    = (const float*)d_in[8];
    const float* ln2_s    = (const float*)d_in[9];
    const float* ln2_b    = (const float*)d_in[10];
    const float* W1       = (const float*)d_in[11];
    const float* b1       = (const float*)d_in[12];
    const float* W2       = (const float*)d_in[13];
    const float* b2       = (const float*)d_in[14];
    const float* gamma_mlp= (const float*)d_in[15];

    // o (f16[65536][128]) aliases d_out (f32[65536][64]); disjoint token partition
    // between k_att writes and k_epi reads/overwrites -> race-free.
    f16* o_buf = (f16*)d_out;
    float* out = (float*)d_out;

    hipLaunchKernelGGL(k_conv, dim3(NPAIRS / 256), dim3(256), 0, stream,
                       Wq, Wkv, Wo, W1, W2);
    hipLaunchKernelGGL(k_att, dim3(2048), dim3(256), 0, stream,
                       x, ln1_s, ln1_b, bkv, o_buf);
    hipLaunchKernelGGL(k_epi, dim3(2048), dim3(256), 0, stream,
                       x, o_buf, bo, gamma, ln2_s, ln2_b, b1, b2, gamma_mlp, out);
}